// Round 1
// baseline (248.945 us; speedup 1.0000x reference)
//
#include <hip/hip_runtime.h>

#define B_ 4096
#define C_ 128
#define D_ 768
#define NTHREADS 256
#define CK 128
#define NCH (D_/CK)
#define M_MAX 96
#define SROW (CK+4)              // padded float stride: 528 B, 16B aligned, banks spread
#define P_MAXP (M_MAX*(M_MAX-1)/2)
#define PPT ((P_MAXP+NTHREADS-1)/NTHREADS)

__device__ __forceinline__ float wave_red(float v){
#pragma unroll
  for (int o = 32; o > 0; o >>= 1) v += __shfl_down(v, o, 64);
  return v;
}

__device__ __forceinline__ float clamp1(float x){ return fminf(fmaxf(x, -1.f), 1.f); }

__device__ __forceinline__ unsigned rotl32(unsigned x, int r){ return (x << r) | (x >> (32 - r)); }

// jax.random.uniform(jax.random.key(1), (B,B), f32), element n = i*B + j.
// Threefry-2x32, key=(0,1), counters iota split in halves: n<half -> word0 of
// TF(n, n+half); else word1 of TF(n-half, n). u = bitcast(bits>>9|0x3f800000)-1.
__device__ float rand_ij(unsigned n){
  const unsigned half = (unsigned)B_ * (unsigned)B_ / 2u;  // 8388608
  unsigned c0, c1; bool hi;
  if (n < half){ c0 = n; c1 = n + half; hi = false; }
  else         { c0 = n - half; c1 = n; hi = true; }
  const unsigned K0 = 0u, K1 = 1u, K2 = 0x1BD11BDBu;  // 0x1BD11BDA ^ 0 ^ 1
  unsigned x0 = c0 + K0, x1 = c1 + K1;
#define TFR(r) { x0 += x1; x1 = rotl32(x1, (r)); x1 ^= x0; }
  TFR(13) TFR(15) TFR(26) TFR(6)  x0 += K1; x1 += K2 + 1u;
  TFR(17) TFR(29) TFR(16) TFR(24) x0 += K2; x1 += K0 + 2u;
  TFR(13) TFR(15) TFR(26) TFR(6)  x0 += K0; x1 += K1 + 3u;
  TFR(17) TFR(29) TFR(16) TFR(24) x0 += K1; x1 += K2 + 4u;
  TFR(13) TFR(15) TFR(26) TFR(6)  x0 += K2; x1 += K0 + 5u;
#undef TFR
  unsigned bits = hi ? x1 : x0;
  return __uint_as_float((bits >> 9) | 0x3F800000u) - 1.0f;
}

// p -> (a,b), a<b<m, row-major upper-tri enumeration. before(a) = a*(2m-1-a)/2.
__device__ __forceinline__ void decode_pair(int p, int m, int* a_, int* b_){
  float fm = (float)(2*m - 1);
  int a = (int)((fm - sqrtf(fm*fm - 8.0f*(float)p)) * 0.5f);
  a = max(0, min(a, m - 2));
  while (a > 0 && (a*(2*m - 1 - a))/2 > p) --a;
  while (((a + 1)*(2*m - 2 - a))/2 <= p) ++a;
  *a_ = a;
  *b_ = a + 1 + (p - (a*(2*m - 1 - a))/2);
}

// ---- slow-path helpers (unreachable on this dataset; correctness insurance) ----
__device__ float pair_dot_g(const float* feat, const float* rnorm, const int* mem, int a, int b){
  const float* ra = feat + (size_t)mem[a] * D_;
  const float* rb = feat + (size_t)mem[b] * D_;
  float s = 0.f;
  for (int k = 0; k < D_; ++k) s = fmaf(ra[k], rb[k], s);
  return s * rnorm[mem[a]] * rnorm[mem[b]];
}
__device__ float ec_dot_g(const float* feat, const float* cent, float rn, float cnc, int gi, int c){
  const float* f = feat + (size_t)gi * D_;
  const float* cc = cent + (size_t)c * D_;
  float s = 0.f;
  for (int k = 0; k < D_; ++k) s = fmaf(f[k], cc[k], s);
  return s * rn * cnc;
}

// ---- kernel 1: row reciprocal norms (features + centers) and label histogram ----
__global__ __launch_bounds__(NTHREADS) void k_norms(
    const float* __restrict__ feat, const float* __restrict__ cent,
    const int* __restrict__ labels, float* __restrict__ rnorm,
    float* __restrict__ cnorm, int* __restrict__ cnt)
{
  const int blk = blockIdx.x;
  const float* src; int row;
  if (blk < B_){ row = blk;      src = feat + (size_t)row * D_; }
  else         { row = blk - B_; src = cent + (size_t)row * D_; }
  float s = 0.f;
  for (int k = threadIdx.x; k < D_; k += NTHREADS){ float v = src[k]; s = fmaf(v, v, s); }
  s = wave_red(s);
  __shared__ float sb[4];
  int wid = threadIdx.x >> 6, lane = threadIdx.x & 63;
  if (lane == 0) sb[wid] = s;
  __syncthreads();
  if (threadIdx.x == 0){
    float t = sb[0] + sb[1] + sb[2] + sb[3];
    float rn = 1.f / fmaxf(sqrtf(t), 1e-12f);
    if (blk < B_){ rnorm[row] = rn; atomicAdd(&cnt[labels[row]], 1); }
    else cnorm[row] = rn;
  }
}

// ---- kernel 2: exclusive scan of 128 counts ----
__global__ void k_scan(const int* __restrict__ cnt, int* __restrict__ offs){
  if (threadIdx.x == 0 && blockIdx.x == 0){
    int acc = 0;
    for (int c = 0; c < C_; ++c){ offs[c] = acc; acc += cnt[c]; }
  }
}

// ---- kernel 3: bucket rows by class ----
__global__ __launch_bounds__(NTHREADS) void k_scatter(
    const int* __restrict__ labels, const int* __restrict__ offs,
    int* __restrict__ cursor, int* __restrict__ members)
{
  int i = blockIdx.x * NTHREADS + threadIdx.x;
  if (i < B_){
    int c = labels[i];
    int p = atomicAdd(&cursor[c], 1);
    members[offs[c] + p] = i;
  }
}

// ---- kernel 4: per-class Gram + median threshold + selected-pair loss ----
__global__ __launch_bounds__(NTHREADS) void k_class(
    const float* __restrict__ feat, const float* __restrict__ cent,
    const float* __restrict__ rnorm, const float* __restrict__ cnorm,
    const int* __restrict__ cnt, const int* __restrict__ offs,
    const int* __restrict__ members, float* __restrict__ acc2)
{
  const int c = blockIdx.x;
  const int m = cnt[c];
  if (m < 2) return;
  const int base = offs[c];
  const int tid = threadIdx.x;

  __shared__ __align__(16) float tile[M_MAX * SROW];  // 50688 B
  __shared__ int   gidx[M_MAX];
  __shared__ float ecv[M_MAX];
  __shared__ float cvec[CK];
  __shared__ float thr_sh;
  __shared__ float redbuf[8];
  float* Sbuf = tile;  // overlay: raw S per pair, used after the dot phase

  const int P = m * (m - 1) / 2;
  const int k0 = (P - 1) >> 1;          // rank of lower median
  const float wc = (float)m;
  float lloss = 0.f, lw = 0.f;

  if (m <= M_MAX){
    for (int a = tid; a < m; a += NTHREADS) gidx[a] = members[base + a];
    __syncthreads();

    int pa[PPT], pb[PPT];
    float acc[PPT];
#pragma unroll
    for (int t = 0; t < PPT; ++t){
      acc[t] = 0.f;
      int p = tid + t * NTHREADS;
      if (p < P){ int a, b; decode_pair(p, m, &a, &b); pa[t] = a; pb[t] = b; }
      else { pa[t] = 0; pb[t] = 1; }
    }

    const float cn = cnorm[c];
    float eca = 0.f;
    for (int ch = 0; ch < NCH; ++ch){
      const int d0 = ch * CK;
      __syncthreads();   // protect tile from previous iteration's readers
      for (int e = tid; e < m * CK; e += NTHREADS){
        int a = e >> 7, k = e & (CK - 1);
        int g = gidx[a];
        tile[a * SROW + k] = feat[(size_t)g * D_ + d0 + k] * rnorm[g];
      }
      if (tid < CK) cvec[tid] = cent[(size_t)c * D_ + d0 + tid] * cn;
      __syncthreads();
#pragma unroll
      for (int t = 0; t < PPT; ++t){
        int p = tid + t * NTHREADS;
        if (p < P){
          const float4* ra = (const float4*)&tile[pa[t] * SROW];
          const float4* rb = (const float4*)&tile[pb[t] * SROW];
          float s = 0.f;
          for (int k = 0; k < CK / 4; ++k){
            float4 x = ra[k], y = rb[k];
            s = fmaf(x.x, y.x, s); s = fmaf(x.y, y.y, s);
            s = fmaf(x.z, y.z, s); s = fmaf(x.w, y.w, s);
          }
          acc[t] += s;
        }
      }
      if (tid < m){   // EC contribution for member tid
        float s = 0.f;
        for (int k = 0; k < CK; ++k) s = fmaf(tile[tid * SROW + k], cvec[k], s);
        eca += s;
      }
    }
    __syncthreads();            // all tile readers done before Sbuf overlay
    if (tid < m) ecv[tid] = eca;
#pragma unroll
    for (int t = 0; t < PPT; ++t){
      int p = tid + t * NTHREADS;
      if (p < P) Sbuf[p] = acc[t];
    }
    __syncthreads();
    // rank-select lower median of pd = 1 - clip(S): value v is the k0-th
    // smallest iff (#pd < v) <= k0 < (#pd < v) + (#pd == v)
#pragma unroll
    for (int t = 0; t < PPT; ++t){
      int p = tid + t * NTHREADS;
      if (p < P){
        float pdp = 1.f - clamp1(acc[t]);
        int lt = 0, eq = 0;
        for (int q = 0; q < P; ++q){       // same q for all lanes -> LDS broadcast
          float pdq = 1.f - clamp1(Sbuf[q]);
          lt += (pdq < pdp); eq += (pdq == pdp);
        }
        if (lt <= k0 && k0 < lt + eq) thr_sh = pdp;
      }
    }
    __syncthreads();
    const float thr = thr_sh;
#pragma unroll
    for (int t = 0; t < PPT; ++t){
      int p = tid + t * NTHREADS;
      if (p < P){
        float S = acc[t];
        float pd = 1.f - clamp1(S);
        if (pd > thr){
          int ga = gidx[pa[t]], gb = gidx[pb[t]];
          float ea = ecv[pa[t]], eb = ecv[pb[t]];
          int i, j; float eci, ecj;
          if (ga < gb){ i = ga; j = gb; eci = ea; ecj = eb; }
          else        { i = gb; j = ga; eci = eb; ecj = ea; }
          float r = rand_ij((unsigned)i * (unsigned)B_ + (unsigned)j);
          float omr = 1.f - r;
          float n2 = r * r + omr * omr + 2.f * r * omr * S;   // raw S here
          float nrm = fmaxf(sqrtf(fmaxf(n2, 0.f)), 1e-12f);
          float dt = clamp1((r * eci + omr * ecj) / nrm);
          lloss += wc * (1.f - dt);
          lw += wc;
        }
      }
    }
  } else {
    // Fallback for m > M_MAX (impossible for this fixed dataset: 11-sigma tail).
    const float cn = cnorm[c];
    for (int p = tid; p < P; p += NTHREADS){
      int a, b; decode_pair(p, m, &a, &b);
      float Sp = pair_dot_g(feat, rnorm, members + base, a, b);
      float pdp = 1.f - clamp1(Sp);
      int lt = 0, eq = 0;
      for (int q = 0; q < P; ++q){
        int a2, b2; decode_pair(q, m, &a2, &b2);
        float pdq = 1.f - clamp1(pair_dot_g(feat, rnorm, members + base, a2, b2));
        lt += (pdq < pdp); eq += (pdq == pdp);
      }
      if (lt <= k0 && k0 < lt + eq) thr_sh = pdp;
    }
    __syncthreads();
    const float thr = thr_sh;
    for (int p = tid; p < P; p += NTHREADS){
      int a, b; decode_pair(p, m, &a, &b);
      float S = pair_dot_g(feat, rnorm, members + base, a, b);
      float pd = 1.f - clamp1(S);
      if (pd > thr){
        int ga = members[base + a], gb = members[base + b];
        if (ga > gb){ int t2 = ga; ga = gb; gb = t2; }
        float eci = ec_dot_g(feat, cent, rnorm[ga], cn, ga, c);
        float ecj = ec_dot_g(feat, cent, rnorm[gb], cn, gb, c);
        float r = rand_ij((unsigned)ga * (unsigned)B_ + (unsigned)gb);
        float omr = 1.f - r;
        float n2 = r * r + omr * omr + 2.f * r * omr * S;
        float nrm = fmaxf(sqrtf(fmaxf(n2, 0.f)), 1e-12f);
        float dt = clamp1((r * eci + omr * ecj) / nrm);
        lloss += wc * (1.f - dt);
        lw += wc;
      }
    }
  }

  lloss = wave_red(lloss); lw = wave_red(lw);
  int wid = tid >> 6, lane = tid & 63;
  if (lane == 0){ redbuf[wid] = lloss; redbuf[4 + wid] = lw; }
  __syncthreads();
  if (tid == 0){
    atomicAdd(&acc2[0], redbuf[0] + redbuf[1] + redbuf[2] + redbuf[3]);
    atomicAdd(&acc2[1], redbuf[4] + redbuf[5] + redbuf[6] + redbuf[7]);
  }
}

// ---- kernel 5: finalize ----
__global__ void k_final(const float* __restrict__ acc2, float* __restrict__ out){
  if (threadIdx.x == 0 && blockIdx.x == 0){
    float l = acc2[0], w = acc2[1];
    out[0] = (w > 0.f) ? (l / w) : 0.f;
  }
}

extern "C" void kernel_launch(void* const* d_in, const int* in_sizes, int n_in,
                              void* d_out, int out_size, void* d_ws, size_t ws_size,
                              hipStream_t stream)
{
  const float* feat   = (const float*)d_in[0];
  const float* cent   = (const float*)d_in[1];
  const int*   labels = (const int*)d_in[2];
  // d_in[3] = cam_ids: unused by the reference computation.

  char* ws = (char*)d_ws;
  int*   cnt     = (int*)(ws + 0);       // 128 ints
  int*   cursor  = (int*)(ws + 512);     // 128 ints
  float* acc2    = (float*)(ws + 1024);  // loss, wsum
  int*   offs    = (int*)(ws + 1088);    // 128 ints
  float* cnorm   = (float*)(ws + 1600);  // 128 floats
  float* rnorm   = (float*)(ws + 2112);  // 4096 floats
  int*   members = (int*)(ws + 18496);   // 4096 ints  (end: 34880 B)

  hipMemsetAsync(ws, 0, 1088, stream);   // zero cnt, cursor, acc2
  k_norms<<<B_ + C_, NTHREADS, 0, stream>>>(feat, cent, labels, rnorm, cnorm, cnt);
  k_scan<<<1, 64, 0, stream>>>(cnt, offs);
  k_scatter<<<(B_ + NTHREADS - 1) / NTHREADS, NTHREADS, 0, stream>>>(labels, offs, cursor, members);
  k_class<<<C_, NTHREADS, 0, stream>>>(feat, cent, rnorm, cnorm, cnt, offs, members, acc2);
  k_final<<<1, 64, 0, stream>>>(acc2, (float*)d_out);
}

// Round 2
// 187.558 us; speedup vs baseline: 1.3273x; 1.3273x over previous
//
#include <hip/hip_runtime.h>

#define B_ 4096
#define C_ 128
#define D_ 768
#define NT 256
#define NT2 512                 // k_select block
#define M_SEL 128               // max class size for fast select path (17 sigma)
#define P_SEL (M_SEL*(M_SEL-1)/2)   // 8128
#define SG_CAP 131072           // pair-buffer capacity (floats)
#define PAIR_BLOCKS 2048

__device__ __forceinline__ float wave_red(float v){
#pragma unroll
  for (int o = 32; o > 0; o >>= 1) v += __shfl_down(v, o, 64);
  return v;
}
__device__ __forceinline__ float clamp1(float x){ return fminf(fmaxf(x, -1.f), 1.f); }
__device__ __forceinline__ unsigned rotl32(unsigned x, int r){ return (x << r) | (x >> (32 - r)); }

// jax.random.uniform(jax.random.key(1),(B,B)) element n: Threefry-2x32 key (0,1),
// counters split in halves. Bit-exact (verified round 1: absmax 0.0).
__device__ float rand_ij(unsigned n){
  const unsigned half = (unsigned)B_ * (unsigned)B_ / 2u;
  unsigned c0, c1; bool hi;
  if (n < half){ c0 = n; c1 = n + half; hi = false; }
  else         { c0 = n - half; c1 = n; hi = true; }
  const unsigned K0 = 0u, K1 = 1u, K2 = 0x1BD11BDBu;
  unsigned x0 = c0 + K0, x1 = c1 + K1;
#define TFR(r) { x0 += x1; x1 = rotl32(x1, (r)); x1 ^= x0; }
  TFR(13) TFR(15) TFR(26) TFR(6)  x0 += K1; x1 += K2 + 1u;
  TFR(17) TFR(29) TFR(16) TFR(24) x0 += K2; x1 += K0 + 2u;
  TFR(13) TFR(15) TFR(26) TFR(6)  x0 += K0; x1 += K1 + 3u;
  TFR(17) TFR(29) TFR(16) TFR(24) x0 += K1; x1 += K2 + 4u;
  TFR(13) TFR(15) TFR(26) TFR(6)  x0 += K2; x1 += K0 + 5u;
#undef TFR
  unsigned bits = hi ? x1 : x0;
  return __uint_as_float((bits >> 9) | 0x3F800000u) - 1.0f;
}

// p -> (a,b), a<b<m, row-major upper-tri. before(a) = a*(2m-1-a)/2.
__device__ __forceinline__ void decode_pair(int p, int m, int* a_, int* b_){
  float fm = (float)(2*m - 1);
  int a = (int)((fm - sqrtf(fm*fm - 8.0f*(float)p)) * 0.5f);
  a = max(0, min(a, m - 2));
  while (a > 0 && (a*(2*m - 1 - a))/2 > p) --a;
  while (((a + 1)*(2*m - 2 - a))/2 <= p) ++a;
  *a_ = a;
  *b_ = a + 1 + (p - (a*(2*m - 1 - a))/2);
}

// ---- slow-path helpers (unreachable on this dataset; correctness insurance) ----
__device__ float pair_dot_g(const float* feat, const float* rnorm, const int* mem, int a, int b){
  const float* ra = feat + (size_t)mem[a] * D_;
  const float* rb = feat + (size_t)mem[b] * D_;
  float s = 0.f;
  for (int k = 0; k < D_; ++k) s = fmaf(ra[k], rb[k], s);
  return s * rnorm[mem[a]] * rnorm[mem[b]];
}

// ---- kernel 1: norms + raw EC dots; one extra block does hist/scan/scatter ----
__global__ __launch_bounds__(NT) void k_norms(
    const float* __restrict__ feat, const float* __restrict__ cent,
    const int* __restrict__ labels, float* __restrict__ rnorm,
    float* __restrict__ cnorm, float* __restrict__ rawEC,
    int* __restrict__ cnt, int* __restrict__ offs, int* __restrict__ poffs,
    int* __restrict__ TP, int* __restrict__ members)
{
  const int blk = blockIdx.x;
  const int tid = threadIdx.x;

  if (blk == B_ + C_){
    // binning block: histogram -> exclusive scans (rows + pairs) -> scatter
    __shared__ int hist[C_], curs[C_], soffs[C_];
    if (tid < C_){ hist[tid] = 0; curs[tid] = 0; }
    __syncthreads();
    for (int i = tid; i < B_; i += NT) atomicAdd(&hist[labels[i]], 1);
    __syncthreads();
    if (tid == 0){
      int acc = 0, pacc = 0;
      for (int c = 0; c < C_; ++c){
        int m = hist[c];
        cnt[c] = m; offs[c] = acc; soffs[c] = acc; poffs[c] = pacc;
        acc += m; pacc += m * (m - 1) / 2;
      }
      poffs[C_] = pacc; *TP = pacc;
    }
    __syncthreads();
    for (int i = tid; i < B_; i += NT){
      int c = labels[i];
      int pos = atomicAdd(&curs[c], 1);
      members[soffs[c] + pos] = i;
    }
    return;
  }

  const bool isF = (blk < B_);
  const int row = isF ? blk : blk - B_;
  const float* src = isF ? (feat + (size_t)row * D_) : (cent + (size_t)row * D_);
  const float* cc  = isF ? (cent + (size_t)labels[row] * D_) : nullptr;

  float ss = 0.f, sd = 0.f;
  for (int k = tid; k < D_; k += NT){
    float v = src[k];
    ss = fmaf(v, v, ss);
    if (isF) sd = fmaf(v, cc[k], sd);
  }
  ss = wave_red(ss); sd = wave_red(sd);
  __shared__ float sb[4], sb2[4];
  int wid = tid >> 6, lane = tid & 63;
  if (lane == 0){ sb[wid] = ss; sb2[wid] = sd; }
  __syncthreads();
  if (tid == 0){
    float t = sb[0] + sb[1] + sb[2] + sb[3];
    float rn = 1.f / fmaxf(sqrtf(t), 1e-12f);
    if (isF){ rnorm[row] = rn; rawEC[row] = sb2[0] + sb2[1] + sb2[2] + sb2[3]; }
    else cnorm[row] = rn;
  }
}

// ---- kernel 2: one wave per pair -> S values ----
__global__ __launch_bounds__(NT) void k_pairs(
    const float* __restrict__ feat, const float* __restrict__ rnorm,
    const int* __restrict__ cnt, const int* __restrict__ offs,
    const int* __restrict__ poffs, const int* __restrict__ TP,
    const int* __restrict__ members, float* __restrict__ Sg, int cap)
{
  __shared__ int spoffs[C_ + 1], scnt[C_], soffs[C_];
  const int tid = threadIdx.x;
  if (tid < C_){ scnt[tid] = cnt[tid]; soffs[tid] = offs[tid]; }
  if (tid <= C_) spoffs[tid] = poffs[tid];
  __syncthreads();

  const int tp = min(TP[0], cap);
  const int lane = tid & 63;
  const int nw = (gridDim.x * NT) >> 6;
  int w = (blockIdx.x * NT + tid) >> 6;

  for (int p = w; p < tp; p += nw){
    int lo = 0, hi = C_;
    while (hi - lo > 1){ int mid = (lo + hi) >> 1; if (spoffs[mid] <= p) lo = mid; else hi = mid; }
    const int c = lo;
    const int pl = p - spoffs[c];
    const int m = scnt[c];
    int a, b; decode_pair(pl, m, &a, &b);
    const int ga = members[soffs[c] + a];
    const int gb = members[soffs[c] + b];
    const float4* ra = (const float4*)(feat + (size_t)ga * D_);
    const float4* rb = (const float4*)(feat + (size_t)gb * D_);
    float s = 0.f;
#pragma unroll
    for (int k = 0; k < D_ / 256; ++k){           // 3 iters: lane + 64k < 192
      float4 x = ra[lane + 64 * k];
      float4 y = rb[lane + 64 * k];
      s = fmaf(x.x, y.x, s); s = fmaf(x.y, y.y, s);
      s = fmaf(x.z, y.z, s); s = fmaf(x.w, y.w, s);
    }
    s = wave_red(s);
    if (lane == 0) Sg[p] = s * rnorm[ga] * rnorm[gb];
  }
}

// ---- kernel 3: per-class median + loss; last block finalizes ----
__global__ __launch_bounds__(NT2) void k_select(
    const float* __restrict__ feat, const float* __restrict__ rnorm,
    const float* __restrict__ cnorm, const float* __restrict__ rawEC,
    const int* __restrict__ cnt, const int* __restrict__ offs,
    const int* __restrict__ poffs, const int* __restrict__ members,
    const float* __restrict__ Sg, int cap,
    float* __restrict__ acc2, int* __restrict__ done, float* __restrict__ out)
{
  const int c = blockIdx.x;
  const int m = cnt[c];
  const int tid = threadIdx.x;

  __shared__ float Sl[P_SEL];
  __shared__ float ec_s[M_SEL];
  __shared__ int   gid_s[M_SEL];
  __shared__ float thr_sh;
  __shared__ float redbuf[16];

  float lloss = 0.f, lw = 0.f;

  if (m >= 2){
    const int base = offs[c];
    const int pbase = poffs[c];
    const int P = m * (m - 1) / 2;
    const int k0 = (P - 1) >> 1;
    const float wc = (float)m;
    const float cn = cnorm[c];
    const bool fast = (m <= M_SEL) && (pbase + P <= cap);

    if (fast){
      for (int p = tid; p < P; p += NT2) Sl[p] = Sg[pbase + p];
      if (tid < m){
        int g = members[base + tid];
        gid_s[tid] = g;
        ec_s[tid] = rawEC[g] * rnorm[g] * cn;
      }
      __syncthreads();
      // exact rank-select of lower median of pd = 1 - clip(S)
      for (int p = tid; p < P; p += NT2){
        float pdp = 1.f - clamp1(Sl[p]);
        int lt = 0, eq = 0;
        for (int q = 0; q < P; ++q){
          float pdq = 1.f - clamp1(Sl[q]);
          lt += (pdq < pdp); eq += (pdq == pdp);
        }
        if (lt <= k0 && k0 < lt + eq) thr_sh = pdp;
      }
      __syncthreads();
      const float thr = thr_sh;
      for (int p = tid; p < P; p += NT2){
        float S = Sl[p];
        float pd = 1.f - clamp1(S);
        if (pd > thr){
          int a, b; decode_pair(p, m, &a, &b);
          int ga = gid_s[a], gb = gid_s[b];
          float ea = ec_s[a], eb = ec_s[b];
          int i, j; float eci, ecj;
          if (ga < gb){ i = ga; j = gb; eci = ea; ecj = eb; }
          else        { i = gb; j = ga; eci = eb; ecj = ea; }
          float r = rand_ij((unsigned)i * (unsigned)B_ + (unsigned)j);
          float omr = 1.f - r;
          float n2 = r * r + omr * omr + 2.f * r * omr * S;   // raw S
          float nrm = fmaxf(sqrtf(fmaxf(n2, 0.f)), 1e-12f);
          float dt = clamp1((r * eci + omr * ecj) / nrm);
          lloss += wc * (1.f - dt);
          lw += wc;
        }
      }
    } else {
      // correctness-only fallback (m > M_SEL or pair-buffer overflow)
      for (int p = tid; p < P; p += NT2){
        int a, b; decode_pair(p, m, &a, &b);
        float Sp = pair_dot_g(feat, rnorm, members + base, a, b);
        float pdp = 1.f - clamp1(Sp);
        int lt = 0, eq = 0;
        for (int q = 0; q < P; ++q){
          int a2, b2; decode_pair(q, m, &a2, &b2);
          float pdq = 1.f - clamp1(pair_dot_g(feat, rnorm, members + base, a2, b2));
          lt += (pdq < pdp); eq += (pdq == pdp);
        }
        if (lt <= k0 && k0 < lt + eq) thr_sh = pdp;
      }
      __syncthreads();
      const float thr = thr_sh;
      for (int p = tid; p < P; p += NT2){
        int a, b; decode_pair(p, m, &a, &b);
        float S = pair_dot_g(feat, rnorm, members + base, a, b);
        float pd = 1.f - clamp1(S);
        if (pd > thr){
          int ga = members[base + a], gb = members[base + b];
          if (ga > gb){ int t2 = ga; ga = gb; gb = t2; }
          float eci = rawEC[ga] * rnorm[ga] * cn;
          float ecj = rawEC[gb] * rnorm[gb] * cn;
          float r = rand_ij((unsigned)ga * (unsigned)B_ + (unsigned)gb);
          float omr = 1.f - r;
          float n2 = r * r + omr * omr + 2.f * r * omr * S;
          float nrm = fmaxf(sqrtf(fmaxf(n2, 0.f)), 1e-12f);
          float dt = clamp1((r * eci + omr * ecj) / nrm);
          lloss += wc * (1.f - dt);
          lw += wc;
        }
      }
    }
  }

  // block reduction + global accumulate + last-block finalize
  lloss = wave_red(lloss); lw = wave_red(lw);
  int wid = tid >> 6, lane = tid & 63;
  if (lane == 0){ redbuf[wid] = lloss; redbuf[8 + wid] = lw; }
  __syncthreads();
  if (tid == 0){
    float tl = 0.f, tw = 0.f;
    for (int i = 0; i < NT2 / 64; ++i){ tl += redbuf[i]; tw += redbuf[8 + i]; }
    if (tl != 0.f || tw != 0.f){
      atomicAdd(&acc2[0], tl);
      atomicAdd(&acc2[1], tw);
    }
    __threadfence();
    int old = atomicAdd(done, 1);
    if (old == C_ - 1){
      float l = atomicAdd(&acc2[0], 0.f);
      float w = atomicAdd(&acc2[1], 0.f);
      out[0] = (w > 0.f) ? (l / w) : 0.f;
    }
  }
}

extern "C" void kernel_launch(void* const* d_in, const int* in_sizes, int n_in,
                              void* d_out, int out_size, void* d_ws, size_t ws_size,
                              hipStream_t stream)
{
  const float* feat   = (const float*)d_in[0];
  const float* cent   = (const float*)d_in[1];
  const int*   labels = (const int*)d_in[2];
  // d_in[3] = cam_ids: unused by the reference computation.

  char* ws = (char*)d_ws;
  float* acc2    = (float*)(ws + 0);       // 2 floats
  int*   done    = (int*)(ws + 8);         // 1 int
  int*   TP      = (int*)(ws + 12);        // 1 int
  int*   cnt     = (int*)(ws + 64);        // 128
  int*   offs    = (int*)(ws + 576);       // 128
  int*   poffs   = (int*)(ws + 1088);      // 129
  float* cnorm   = (float*)(ws + 1664);    // 128
  float* rnorm   = (float*)(ws + 2176);    // 4096
  float* rawEC   = (float*)(ws + 18560);   // 4096
  int*   members = (int*)(ws + 34944);     // 4096
  float* Sg      = (float*)(ws + 51328);   // up to SG_CAP floats

  long long avail = (long long)ws_size - 51328;
  int cap = (avail > 0) ? (int)min(avail / 4, (long long)SG_CAP) : 0;

  hipMemsetAsync(ws, 0, 64, stream);  // acc2, done, TP
  k_norms<<<B_ + C_ + 1, NT, 0, stream>>>(feat, cent, labels, rnorm, cnorm, rawEC,
                                          cnt, offs, poffs, TP, members);
  k_pairs<<<PAIR_BLOCKS, NT, 0, stream>>>(feat, rnorm, cnt, offs, poffs, TP, members, Sg, cap);
  k_select<<<C_, NT2, 0, stream>>>(feat, rnorm, cnorm, rawEC, cnt, offs, poffs,
                                   members, Sg, cap, acc2, done, (float*)d_out);
}

// Round 3
// 158.263 us; speedup vs baseline: 1.5730x; 1.1851x over previous
//
#include <hip/hip_runtime.h>

#define B_ 4096
#define C_ 128
#define D_ 768
#define NT 256
#define NT2 512                 // k_select block
#define M_SEL 128               // max class size for fast select path (17 sigma)
#define P_SEL (M_SEL*(M_SEL-1)/2)   // 8128
#define SG_CAP 131072           // pair-buffer capacity (floats)
#define PAIR_BLOCKS 2048

__device__ __forceinline__ float wave_red(float v){
#pragma unroll
  for (int o = 32; o > 0; o >>= 1) v += __shfl_down(v, o, 64);
  return v;
}
__device__ __forceinline__ float clamp1(float x){ return fminf(fmaxf(x, -1.f), 1.f); }
__device__ __forceinline__ unsigned rotl32(unsigned x, int r){ return (x << r) | (x >> (32 - r)); }

// jax.random.uniform(jax.random.key(1),(B,B)) element n: Threefry-2x32 key (0,1),
// counters split in halves. Bit-exact (verified round 1: absmax 0.0).
__device__ float rand_ij(unsigned n){
  const unsigned half = (unsigned)B_ * (unsigned)B_ / 2u;
  unsigned c0, c1; bool hi;
  if (n < half){ c0 = n; c1 = n + half; hi = false; }
  else         { c0 = n - half; c1 = n; hi = true; }
  const unsigned K0 = 0u, K1 = 1u, K2 = 0x1BD11BDBu;
  unsigned x0 = c0 + K0, x1 = c1 + K1;
#define TFR(r) { x0 += x1; x1 = rotl32(x1, (r)); x1 ^= x0; }
  TFR(13) TFR(15) TFR(26) TFR(6)  x0 += K1; x1 += K2 + 1u;
  TFR(17) TFR(29) TFR(16) TFR(24) x0 += K2; x1 += K0 + 2u;
  TFR(13) TFR(15) TFR(26) TFR(6)  x0 += K0; x1 += K1 + 3u;
  TFR(17) TFR(29) TFR(16) TFR(24) x0 += K1; x1 += K2 + 4u;
  TFR(13) TFR(15) TFR(26) TFR(6)  x0 += K2; x1 += K0 + 5u;
#undef TFR
  unsigned bits = hi ? x1 : x0;
  return __uint_as_float((bits >> 9) | 0x3F800000u) - 1.0f;
}

// p -> (a,b), a<b<m, row-major upper-tri. before(a) = a*(2m-1-a)/2.
__device__ __forceinline__ void decode_pair(int p, int m, int* a_, int* b_){
  float fm = (float)(2*m - 1);
  int a = (int)((fm - sqrtf(fm*fm - 8.0f*(float)p)) * 0.5f);
  a = max(0, min(a, m - 2));
  while (a > 0 && (a*(2*m - 1 - a))/2 > p) --a;
  while (((a + 1)*(2*m - 2 - a))/2 <= p) ++a;
  *a_ = a;
  *b_ = a + 1 + (p - (a*(2*m - 1 - a))/2);
}

// ---- slow-path helpers (unreachable on this dataset; correctness insurance) ----
__device__ float pair_dot_g(const float* feat, const float* rnorm, const int* mem, int a, int b){
  const float* ra = feat + (size_t)mem[a] * D_;
  const float* rb = feat + (size_t)mem[b] * D_;
  float s = 0.f;
  for (int k = 0; k < D_; ++k) s = fmaf(ra[k], rb[k], s);
  return s * rnorm[mem[a]] * rnorm[mem[b]];
}

// ---- kernel 1: norms + raw EC dots; one extra block does hist/scan/scatter ----
__global__ __launch_bounds__(NT) void k_norms(
    const float* __restrict__ feat, const float* __restrict__ cent,
    const int* __restrict__ labels, float* __restrict__ rnorm,
    float* __restrict__ cnorm, float* __restrict__ rawEC,
    int* __restrict__ cnt, int* __restrict__ offs, int* __restrict__ poffs,
    int* __restrict__ TP, int* __restrict__ members)
{
  const int blk = blockIdx.x;
  const int tid = threadIdx.x;

  if (blk == B_ + C_){
    // binning block: histogram -> exclusive scans (rows + pairs) -> scatter
    __shared__ int hist[C_], curs[C_], soffs[C_];
    if (tid < C_){ hist[tid] = 0; curs[tid] = 0; }
    __syncthreads();
    for (int i = tid; i < B_; i += NT) atomicAdd(&hist[labels[i]], 1);
    __syncthreads();
    if (tid == 0){
      int acc = 0, pacc = 0;
      for (int c = 0; c < C_; ++c){
        int m = hist[c];
        cnt[c] = m; offs[c] = acc; soffs[c] = acc; poffs[c] = pacc;
        acc += m; pacc += m * (m - 1) / 2;
      }
      poffs[C_] = pacc; *TP = pacc;
    }
    __syncthreads();
    for (int i = tid; i < B_; i += NT){
      int c = labels[i];
      int pos = atomicAdd(&curs[c], 1);
      members[soffs[c] + pos] = i;
    }
    return;
  }

  const bool isF = (blk < B_);
  const int row = isF ? blk : blk - B_;
  const float* src = isF ? (feat + (size_t)row * D_) : (cent + (size_t)row * D_);
  const float* cc  = isF ? (cent + (size_t)labels[row] * D_) : nullptr;

  float ss = 0.f, sd = 0.f;
  for (int k = tid; k < D_; k += NT){
    float v = src[k];
    ss = fmaf(v, v, ss);
    if (isF) sd = fmaf(v, cc[k], sd);
  }
  ss = wave_red(ss); sd = wave_red(sd);
  __shared__ float sb[4], sb2[4];
  int wid = tid >> 6, lane = tid & 63;
  if (lane == 0){ sb[wid] = ss; sb2[wid] = sd; }
  __syncthreads();
  if (tid == 0){
    float t = sb[0] + sb[1] + sb[2] + sb[3];
    float rn = 1.f / fmaxf(sqrtf(t), 1e-12f);
    if (isF){ rnorm[row] = rn; rawEC[row] = sb2[0] + sb2[1] + sb2[2] + sb2[3]; }
    else cnorm[row] = rn;
  }
}

// ---- kernel 2: one wave per pair -> S values ----
__global__ __launch_bounds__(NT) void k_pairs(
    const float* __restrict__ feat, const float* __restrict__ rnorm,
    const int* __restrict__ cnt, const int* __restrict__ offs,
    const int* __restrict__ poffs, const int* __restrict__ TP,
    const int* __restrict__ members, float* __restrict__ Sg, int cap)
{
  __shared__ int spoffs[C_ + 1], scnt[C_], soffs[C_];
  const int tid = threadIdx.x;
  if (tid < C_){ scnt[tid] = cnt[tid]; soffs[tid] = offs[tid]; }
  if (tid <= C_) spoffs[tid] = poffs[tid];
  __syncthreads();

  const int tp = min(TP[0], cap);
  const int lane = tid & 63;
  const int nw = (gridDim.x * NT) >> 6;
  int w = (blockIdx.x * NT + tid) >> 6;

  for (int p = w; p < tp; p += nw){
    int lo = 0, hi = C_;
    while (hi - lo > 1){ int mid = (lo + hi) >> 1; if (spoffs[mid] <= p) lo = mid; else hi = mid; }
    const int c = lo;
    const int pl = p - spoffs[c];
    const int m = scnt[c];
    int a, b; decode_pair(pl, m, &a, &b);
    const int ga = members[soffs[c] + a];
    const int gb = members[soffs[c] + b];
    const float4* ra = (const float4*)(feat + (size_t)ga * D_);
    const float4* rb = (const float4*)(feat + (size_t)gb * D_);
    float s = 0.f;
#pragma unroll
    for (int k = 0; k < D_ / 256; ++k){           // 3 iters: lane + 64k < 192
      float4 x = ra[lane + 64 * k];
      float4 y = rb[lane + 64 * k];
      s = fmaf(x.x, y.x, s); s = fmaf(x.y, y.y, s);
      s = fmaf(x.z, y.z, s); s = fmaf(x.w, y.w, s);
    }
    s = wave_red(s);
    if (lane == 0) Sg[p] = s * rnorm[ga] * rnorm[gb];
  }
}

// ---- kernel 3: per-class median + loss; last block finalizes ----
__global__ __launch_bounds__(NT2) void k_select(
    const float* __restrict__ feat, const float* __restrict__ rnorm,
    const float* __restrict__ cnorm, const float* __restrict__ rawEC,
    const int* __restrict__ cnt, const int* __restrict__ offs,
    const int* __restrict__ poffs, const int* __restrict__ members,
    const float* __restrict__ Sg, int cap,
    float* __restrict__ acc2, int* __restrict__ done, float* __restrict__ out)
{
  const int c = blockIdx.x;
  const int m = cnt[c];
  const int tid = threadIdx.x;

  __shared__ __align__(16) float Sl[P_SEL];   // raw S per pair
  __shared__ __align__(16) float Pd[P_SEL];   // pd = 1 - clip(S), for rank count
  __shared__ float ec_s[M_SEL];
  __shared__ int   gid_s[M_SEL];
  __shared__ float thr_sh;
  __shared__ float redbuf[16];

  float lloss = 0.f, lw = 0.f;

  if (m >= 2){
    const int base = offs[c];
    const int pbase = poffs[c];
    const int P = m * (m - 1) / 2;
    const int k0 = (P - 1) >> 1;
    const float wc = (float)m;
    const float cn = cnorm[c];
    const bool fast = (m <= M_SEL) && (pbase + P <= cap);

    if (fast){
      for (int p = tid; p < P; p += NT2){
        float s = Sg[pbase + p];
        Sl[p] = s;
        Pd[p] = 1.f - clamp1(s);
      }
      if (tid < m){
        int g = members[base + tid];
        gid_s[tid] = g;
        ec_s[tid] = rawEC[g] * rnorm[g] * cn;
      }
      __syncthreads();
      // exact rank-select of lower median of pd; float4 broadcast reads keep
      // the ds_read pipeline full (throughput ~3 cyc/elem vs 120-cyc latency)
      const float4* Pd4 = (const float4*)Pd;
      const int nq4 = P >> 2;
      for (int p = tid; p < P; p += NT2){
        const float pdp = Pd[p];
        int lt = 0, eq = 0;
#pragma unroll 4
        for (int q4 = 0; q4 < nq4; ++q4){
          float4 v = Pd4[q4];
          lt += (v.x < pdp) + (v.y < pdp) + (v.z < pdp) + (v.w < pdp);
          eq += (v.x == pdp) + (v.y == pdp) + (v.z == pdp) + (v.w == pdp);
        }
        for (int q = nq4 << 2; q < P; ++q){
          float pdq = Pd[q];
          lt += (pdq < pdp); eq += (pdq == pdp);
        }
        if (lt <= k0 && k0 < lt + eq) thr_sh = pdp;
      }
      __syncthreads();
      const float thr = thr_sh;
      for (int p = tid; p < P; p += NT2){
        float S = Sl[p];
        float pd = Pd[p];
        if (pd > thr){
          int a, b; decode_pair(p, m, &a, &b);
          int ga = gid_s[a], gb = gid_s[b];
          float ea = ec_s[a], eb = ec_s[b];
          int i, j; float eci, ecj;
          if (ga < gb){ i = ga; j = gb; eci = ea; ecj = eb; }
          else        { i = gb; j = ga; eci = eb; ecj = ea; }
          float r = rand_ij((unsigned)i * (unsigned)B_ + (unsigned)j);
          float omr = 1.f - r;
          float n2 = r * r + omr * omr + 2.f * r * omr * S;   // raw S
          float nrm = fmaxf(sqrtf(fmaxf(n2, 0.f)), 1e-12f);
          float dt = clamp1((r * eci + omr * ecj) / nrm);
          lloss += wc * (1.f - dt);
          lw += wc;
        }
      }
    } else {
      // correctness-only fallback (m > M_SEL or pair-buffer overflow)
      for (int p = tid; p < P; p += NT2){
        int a, b; decode_pair(p, m, &a, &b);
        float Sp = pair_dot_g(feat, rnorm, members + base, a, b);
        float pdp = 1.f - clamp1(Sp);
        int lt = 0, eq = 0;
        for (int q = 0; q < P; ++q){
          int a2, b2; decode_pair(q, m, &a2, &b2);
          float pdq = 1.f - clamp1(pair_dot_g(feat, rnorm, members + base, a2, b2));
          lt += (pdq < pdp); eq += (pdq == pdp);
        }
        if (lt <= k0 && k0 < lt + eq) thr_sh = pdp;
      }
      __syncthreads();
      const float thr = thr_sh;
      for (int p = tid; p < P; p += NT2){
        int a, b; decode_pair(p, m, &a, &b);
        float S = pair_dot_g(feat, rnorm, members + base, a, b);
        float pd = 1.f - clamp1(S);
        if (pd > thr){
          int ga = members[base + a], gb = members[base + b];
          if (ga > gb){ int t2 = ga; ga = gb; gb = t2; }
          float eci = rawEC[ga] * rnorm[ga] * cn;
          float ecj = rawEC[gb] * rnorm[gb] * cn;
          float r = rand_ij((unsigned)ga * (unsigned)B_ + (unsigned)gb);
          float omr = 1.f - r;
          float n2 = r * r + omr * omr + 2.f * r * omr * S;
          float nrm = fmaxf(sqrtf(fmaxf(n2, 0.f)), 1e-12f);
          float dt = clamp1((r * eci + omr * ecj) / nrm);
          lloss += wc * (1.f - dt);
          lw += wc;
        }
      }
    }
  }

  // block reduction + global accumulate + last-block finalize
  lloss = wave_red(lloss); lw = wave_red(lw);
  int wid = tid >> 6, lane = tid & 63;
  if (lane == 0){ redbuf[wid] = lloss; redbuf[8 + wid] = lw; }
  __syncthreads();
  if (tid == 0){
    float tl = 0.f, tw = 0.f;
    for (int i = 0; i < NT2 / 64; ++i){ tl += redbuf[i]; tw += redbuf[8 + i]; }
    if (tl != 0.f || tw != 0.f){
      atomicAdd(&acc2[0], tl);
      atomicAdd(&acc2[1], tw);
    }
    __threadfence();
    int old = atomicAdd(done, 1);
    if (old == C_ - 1){
      float l = atomicAdd(&acc2[0], 0.f);
      float w = atomicAdd(&acc2[1], 0.f);
      out[0] = (w > 0.f) ? (l / w) : 0.f;
    }
  }
}

extern "C" void kernel_launch(void* const* d_in, const int* in_sizes, int n_in,
                              void* d_out, int out_size, void* d_ws, size_t ws_size,
                              hipStream_t stream)
{
  const float* feat   = (const float*)d_in[0];
  const float* cent   = (const float*)d_in[1];
  const int*   labels = (const int*)d_in[2];
  // d_in[3] = cam_ids: unused by the reference computation.

  char* ws = (char*)d_ws;
  float* acc2    = (float*)(ws + 0);       // 2 floats
  int*   done    = (int*)(ws + 8);         // 1 int
  int*   TP      = (int*)(ws + 12);        // 1 int
  int*   cnt     = (int*)(ws + 64);        // 128
  int*   offs    = (int*)(ws + 576);       // 128
  int*   poffs   = (int*)(ws + 1088);      // 129
  float* cnorm   = (float*)(ws + 1664);    // 128
  float* rnorm   = (float*)(ws + 2176);    // 4096
  float* rawEC   = (float*)(ws + 18560);   // 4096
  int*   members = (int*)(ws + 34944);     // 4096
  float* Sg      = (float*)(ws + 51328);   // up to SG_CAP floats

  long long avail = (long long)ws_size - 51328;
  int cap = (avail > 0) ? (int)min(avail / 4, (long long)SG_CAP) : 0;

  hipMemsetAsync(ws, 0, 64, stream);  // acc2, done, TP
  k_norms<<<B_ + C_ + 1, NT, 0, stream>>>(feat, cent, labels, rnorm, cnorm, rawEC,
                                          cnt, offs, poffs, TP, members);
  k_pairs<<<PAIR_BLOCKS, NT, 0, stream>>>(feat, rnorm, cnt, offs, poffs, TP, members, Sg, cap);
  k_select<<<C_, NT2, 0, stream>>>(feat, rnorm, cnorm, rawEC, cnt, offs, poffs,
                                   members, Sg, cap, acc2, done, (float*)d_out);
}